// Round 1
// baseline (849.879 us; speedup 1.0000x reference)
//
#include <hip/hip_runtime.h>
#include <math.h>

#define NN 100000
#define NE 1600000
#define DH 128
#define DOUT 32

// ---------------- CSR build ----------------

__global__ void k_count(const int* __restrict__ dst, int* __restrict__ cnt) {
  int e = blockIdx.x * 256 + threadIdx.x;
  if (e < NE) {
    int d = dst[e];
    d = d < 0 ? 0 : (d >= NN ? NN - 1 : d);   // defensive clamp
    atomicAdd(&cnt[d], 1);
  }
}

#define CHUNK 1024

__global__ void k_scan_sum(const int* __restrict__ cnt, int* __restrict__ parts) {
  __shared__ int sd[256];
  int b = blockIdx.x, t = threadIdx.x;
  int base = b * CHUNK;
  int s = 0;
  for (int i = t; i < CHUNK; i += 256) {
    int idx = base + i;
    s += (idx < NN) ? cnt[idx] : 0;
  }
  sd[t] = s;
  __syncthreads();
  for (int st = 128; st; st >>= 1) {
    if (t < st) sd[t] += sd[t + st];
    __syncthreads();
  }
  if (t == 0) parts[b] = sd[0];
}

__global__ void k_scan_top(int* __restrict__ parts, int nb, int* __restrict__ csroff) {
  if (blockIdx.x == 0 && threadIdx.x == 0) {
    int acc = 0;
    for (int i = 0; i < nb; i++) { int v = parts[i]; parts[i] = acc; acc += v; }
    csroff[NN] = acc;   // == NE
  }
}

__global__ void k_scan_chunks(const int* __restrict__ cnt, const int* __restrict__ parts,
                              int* __restrict__ csroff) {
  __shared__ int sums[256];
  int b = blockIdx.x, t = threadIdx.x;
  int base = b * CHUNK;
  int v[4]; int loc = 0;
  #pragma unroll
  for (int i = 0; i < 4; i++) {
    int idx = base + t * 4 + i;
    v[i] = (idx < NN) ? cnt[idx] : 0;
    loc += v[i];
  }
  sums[t] = loc;
  __syncthreads();
  for (int st = 1; st < 256; st <<= 1) {
    int x = (t >= st) ? sums[t - st] : 0;
    __syncthreads();
    sums[t] += x;
    __syncthreads();
  }
  int run = (t ? sums[t - 1] : 0) + parts[b];
  #pragma unroll
  for (int i = 0; i < 4; i++) {
    int idx = base + t * 4 + i;
    if (idx < NN) csroff[idx] = run;
    run += v[i];
  }
}

__global__ void k_invdeg(const int* __restrict__ cnt, float* __restrict__ invd) {
  int i = blockIdx.x * 256 + threadIdx.x;
  if (i < NN) {
    int d = cnt[i];
    invd[i] = 1.0f / (float)(d < 1 ? 1 : d);
  }
}

__global__ void k_fill(const int* __restrict__ src, const int* __restrict__ dst,
                       const int* __restrict__ csroff, int* __restrict__ cursor,
                       int* __restrict__ csrsrc) {
  int e = blockIdx.x * 256 + threadIdx.x;
  if (e < NE) {
    int d = dst[e];
    d = d < 0 ? 0 : (d >= NN ? NN - 1 : d);
    int s = src[e];
    s = s < 0 ? 0 : (s >= NN ? NN - 1 : s);
    int p = csroff[d] + atomicAdd(&cursor[d], 1);
    csrsrc[p] = s;
  }
}

// ---------------- GEMM: [NN,128] @ [128,128] (+bias) ----------------
// block tile: 128 nodes x 128 cols; 256 thr = 16 tx (8 cols) x 16 ty (8 nodes)
// k-chunked (KC=16) staging of both X (transposed) and W into LDS.
// W LDS layout swizzled f(c) = c + 4*(c>>5) to break the 4-way conflict on
// the 8*tx f4 read pattern down to 2-way (free).

__device__ __forceinline__ int wswz(int c) { return c + ((c >> 5) << 2); }

__global__ __launch_bounds__(256) void k_gemm128(
    const float* __restrict__ A, const float* __restrict__ W,
    const float* __restrict__ bias, float* __restrict__ out) {
  __shared__ float sW[16 * 140];
  __shared__ float sX[16 * 132];
  int tid = threadIdx.x;
  int nb  = blockIdx.x * 128;
  int tx = tid & 15, ty = tid >> 4;

  float acc[8][8];
  #pragma unroll
  for (int i = 0; i < 8; i++)
    #pragma unroll
    for (int j = 0; j < 8; j++) acc[i][j] = 0.0f;

  for (int kb = 0; kb < 8; kb++) {
    __syncthreads();
    // stage X chunk: 128 nodes x 16 k, transposed into sX[k][node]
    #pragma unroll
    for (int i = 0; i < 2; i++) {
      int j = i * 256 + tid;            // 0..511 f4s
      int node = j >> 2;
      int k4 = (j & 3) * 4;
      float4 xv = make_float4(0.f, 0.f, 0.f, 0.f);
      int gn = nb + node;
      if (gn < NN) xv = *(const float4*)&A[gn * 128 + kb * 16 + k4];
      sX[(k4 + 0) * 132 + node] = xv.x;
      sX[(k4 + 1) * 132 + node] = xv.y;
      sX[(k4 + 2) * 132 + node] = xv.z;
      sX[(k4 + 3) * 132 + node] = xv.w;
    }
    // stage W chunk: 16 k x 128 c
    #pragma unroll
    for (int i = 0; i < 2; i++) {
      int j = i * 256 + tid;            // 0..511 f4s
      int k = j >> 5;
      int c4 = (j & 31) * 4;
      float4 wv = *(const float4*)&W[(kb * 16 + k) * 128 + c4];
      *(float4*)&sW[k * 140 + wswz(c4)] = wv;
    }
    __syncthreads();
    #pragma unroll
    for (int kk = 0; kk < 16; kk++) {
      float4 xa = *(const float4*)&sX[kk * 132 + 8 * ty];
      float4 xb = *(const float4*)&sX[kk * 132 + 8 * ty + 4];
      int cb = 8 * tx;
      float4 wa = *(const float4*)&sW[kk * 140 + wswz(cb)];
      float4 wb = *(const float4*)&sW[kk * 140 + wswz(cb + 4)];
      float xv[8] = {xa.x, xa.y, xa.z, xa.w, xb.x, xb.y, xb.z, xb.w};
      float wv[8] = {wa.x, wa.y, wa.z, wa.w, wb.x, wb.y, wb.z, wb.w};
      #pragma unroll
      for (int i = 0; i < 8; i++)
        #pragma unroll
        for (int j = 0; j < 8; j++)
          acc[i][j] += xv[i] * wv[j];
    }
  }
  // epilogue
  float bs[8];
  #pragma unroll
  for (int j = 0; j < 8; j++) bs[j] = bias ? bias[8 * tx + j] : 0.0f;
  #pragma unroll
  for (int i = 0; i < 8; i++) {
    int gn = nb + 8 * ty + i;
    if (gn < NN) {
      float4 o0 = make_float4(acc[i][0] + bs[0], acc[i][1] + bs[1],
                              acc[i][2] + bs[2], acc[i][3] + bs[3]);
      float4 o1 = make_float4(acc[i][4] + bs[4], acc[i][5] + bs[5],
                              acc[i][6] + bs[6], acc[i][7] + bs[7]);
      *(float4*)&out[gn * 128 + 8 * tx]     = o0;
      *(float4*)&out[gn * 128 + 8 * tx + 4] = o1;
    }
  }
}

// ---------------- dual GEMM: [NN,128] @ [128,32] for Wl2 and Wr2 ----------------
// block: 64 nodes x 32 cols, 128 threads = 16 ng (4 nodes) x 8 cg (4 cols)
// 2 k-chunks of 64.

__global__ __launch_bounds__(128) void k_gemm32(
    const float* __restrict__ A, const float* __restrict__ Wl,
    const float* __restrict__ Wr, const float* __restrict__ bias,
    float* __restrict__ yl, float* __restrict__ yr) {
  __shared__ float sAT[64 * 68];   // [k][node], stride 68
  __shared__ float sWl[64 * 36];   // [k][c], stride 36
  __shared__ float sWr[64 * 36];
  int tid = threadIdx.x;
  int nb  = blockIdx.x * 64;
  int ng = tid >> 3;   // 0..15 -> nodes 4*ng..4*ng+3
  int cg = tid & 7;    // cols 4*cg..

  float accl[4][4], accr[4][4];
  #pragma unroll
  for (int i = 0; i < 4; i++)
    #pragma unroll
    for (int j = 0; j < 4; j++) { accl[i][j] = 0.f; accr[i][j] = 0.f; }

  for (int kb = 0; kb < 2; kb++) {
    __syncthreads();
    // stage A chunk 64 nodes x 64 k transposed
    #pragma unroll
    for (int i = 0; i < 8; i++) {
      int j = i * 128 + tid;           // 0..1023 f4s
      int node = j >> 4;
      int k4 = (j & 15) * 4;
      float4 v = make_float4(0.f, 0.f, 0.f, 0.f);
      int gn = nb + node;
      if (gn < NN) v = *(const float4*)&A[gn * 128 + kb * 64 + k4];
      sAT[(k4 + 0) * 68 + node] = v.x;
      sAT[(k4 + 1) * 68 + node] = v.y;
      sAT[(k4 + 2) * 68 + node] = v.z;
      sAT[(k4 + 3) * 68 + node] = v.w;
    }
    // stage W chunks 64 k x 32 c
    #pragma unroll
    for (int i = 0; i < 4; i++) {
      int j = i * 128 + tid;           // 0..511 f4s
      int k = j >> 3;
      int c4 = (j & 7) * 4;
      *(float4*)&sWl[k * 36 + c4] = *(const float4*)&Wl[(kb * 64 + k) * 32 + c4];
      *(float4*)&sWr[k * 36 + c4] = *(const float4*)&Wr[(kb * 64 + k) * 32 + c4];
    }
    __syncthreads();
    #pragma unroll 8
    for (int kk = 0; kk < 64; kk++) {
      float4 a  = *(const float4*)&sAT[kk * 68 + 4 * ng];
      float4 wl = *(const float4*)&sWl[kk * 36 + 4 * cg];
      float4 wr = *(const float4*)&sWr[kk * 36 + 4 * cg];
      float av[4] = {a.x, a.y, a.z, a.w};
      float wlv[4] = {wl.x, wl.y, wl.z, wl.w};
      float wrv[4] = {wr.x, wr.y, wr.z, wr.w};
      #pragma unroll
      for (int i = 0; i < 4; i++)
        #pragma unroll
        for (int j = 0; j < 4; j++) {
          accl[i][j] += av[i] * wlv[j];
          accr[i][j] += av[i] * wrv[j];
        }
    }
  }
  float bs[4];
  #pragma unroll
  for (int j = 0; j < 4; j++) bs[j] = bias[4 * cg + j];
  #pragma unroll
  for (int i = 0; i < 4; i++) {
    int gn = nb + 4 * ng + i;
    if (gn < NN) {
      *(float4*)&yl[gn * 32 + 4 * cg] =
          make_float4(accl[i][0], accl[i][1], accl[i][2], accl[i][3]);
      *(float4*)&yr[gn * 32 + 4 * cg] =
          make_float4(accr[i][0] + bs[0], accr[i][1] + bs[1],
                      accr[i][2] + bs[2], accr[i][3] + bs[3]);
    }
  }
}

// ---------------- pull aggregation, 128-dim: one wave per node ----------------
// h_next[i] = act( (sum_{e in CSR[i]} yl[src_e]) * invd[i] + yr[i] )

__global__ __launch_bounds__(256) void k_agg128(
    const float* __restrict__ yl, const float* __restrict__ yr,
    const int* __restrict__ off, const int* __restrict__ csr,
    const float* __restrict__ invd, float* __restrict__ out, int relu) {
  int wid  = (blockIdx.x * 256 + threadIdx.x) >> 6;
  int lane = threadIdx.x & 63;
  if (wid >= NN) return;
  int beg = off[wid], end = off[wid + 1];
  const float2* ylp = (const float2*)yl;
  float2 a0 = make_float2(0.f, 0.f), a1 = make_float2(0.f, 0.f);
  int e = beg;
  for (; e + 1 < end; e += 2) {
    int s0 = csr[e], s1 = csr[e + 1];
    float2 v0 = ylp[s0 * 64 + lane];
    float2 v1 = ylp[s1 * 64 + lane];
    a0.x += v0.x; a0.y += v0.y;
    a1.x += v1.x; a1.y += v1.y;
  }
  if (e < end) {
    int s = csr[e];
    float2 v = ylp[s * 64 + lane];
    a0.x += v.x; a0.y += v.y;
  }
  float sc = invd[wid];
  float2 r = ((const float2*)yr)[wid * 64 + lane];
  float vx = (a0.x + a1.x) * sc + r.x;
  float vy = (a0.y + a1.y) * sc + r.y;
  if (relu) { vx = fmaxf(vx, 0.f); vy = fmaxf(vy, 0.f); }
  ((float2*)out)[wid * 64 + lane] = make_float2(vx, vy);
}

// ---------------- 32-dim aggregation + bias + log_softmax (fused) ----------------
// 32 lanes per node (2 nodes per wave).

__global__ __launch_bounds__(256) void k_agg32_lsm(
    const float* __restrict__ yl, const float* __restrict__ yr,
    const int* __restrict__ off, const int* __restrict__ csr,
    const float* __restrict__ invd, float* __restrict__ out) {
  int row  = (blockIdx.x * 256 + threadIdx.x) >> 5;
  int lane = threadIdx.x & 31;
  if (row >= NN) return;
  int beg = off[row], end = off[row + 1];
  float acc = 0.f;
  for (int e = beg; e < end; e++) {
    int s = csr[e];
    acc += yl[s * 32 + lane];
  }
  float v = acc * invd[row] + yr[row * 32 + lane];
  // log_softmax across the 32-lane group
  float m = v;
  #pragma unroll
  for (int o = 16; o; o >>= 1) m = fmaxf(m, __shfl_xor(m, o, 32));
  float ex = expf(v - m);
  float s = ex;
  #pragma unroll
  for (int o = 16; o; o >>= 1) s += __shfl_xor(s, o, 32);
  out[row * 32 + lane] = v - m - logf(s);
}

// ---------------- launch ----------------

extern "C" void kernel_launch(void* const* d_in, const int* in_sizes, int n_in,
                              void* d_out, int out_size, void* d_ws, size_t ws_size,
                              hipStream_t stream) {
  (void)in_sizes; (void)n_in; (void)out_size; (void)ws_size;
  const float* x   = (const float*)d_in[0];
  const int*   ei  = (const int*)d_in[1];
  const float* Wl0 = (const float*)d_in[2];
  const float* bl0 = (const float*)d_in[3];
  const float* Wr0 = (const float*)d_in[4];
  const float* Wl1 = (const float*)d_in[5];
  const float* bl1 = (const float*)d_in[6];
  const float* Wr1 = (const float*)d_in[7];
  const float* Wl2 = (const float*)d_in[8];
  const float* bl2 = (const float*)d_in[9];
  const float* Wr2 = (const float*)d_in[10];
  const int* srcI = ei;
  const int* dstI = ei + NE;

  char* w = (char*)d_ws;
  int*   cnt    = (int*)(w + 0);
  int*   cursor = (int*)(w + (512 << 10));
  int*   csroff = (int*)(w + (1024 << 10));
  float* invd   = (float*)(w + (1536 << 10));
  int*   parts  = (int*)(w + (2048 << 10));
  int*   csrsrc = (int*)(w + (2560 << 10));
  float* yl     = (float*)(w + (size_t)(10)  * 1024 * 1024);
  float* yr     = (float*)(w + (size_t)(64)  * 1024 * 1024);
  float* hb     = (float*)(w + (size_t)(118) * 1024 * 1024);
  // total footprint ~170 MB

  hipMemsetAsync(cnt, 0, NN * sizeof(int), stream);
  hipMemsetAsync(cursor, 0, NN * sizeof(int), stream);

  int nch = (NN + CHUNK - 1) / CHUNK;   // 98
  k_count<<<(NE + 255) / 256, 256, 0, stream>>>(dstI, cnt);
  k_scan_sum<<<nch, 256, 0, stream>>>(cnt, parts);
  k_scan_top<<<1, 1, 0, stream>>>(parts, nch, csroff);
  k_scan_chunks<<<nch, 256, 0, stream>>>(cnt, parts, csroff);
  k_invdeg<<<(NN + 255) / 256, 256, 0, stream>>>(cnt, invd);
  k_fill<<<(NE + 255) / 256, 256, 0, stream>>>(srcI, dstI, csroff, cursor, csrsrc);

  dim3 gg((NN + 127) / 128);
  // layer 0
  k_gemm128<<<gg, 256, 0, stream>>>(x, Wl0, nullptr, yl);
  k_gemm128<<<gg, 256, 0, stream>>>(x, Wr0, bl0, yr);
  k_agg128<<<(NN * 64) / 256, 256, 0, stream>>>(yl, yr, csroff, csrsrc, invd, hb, 1);
  // layer 1
  k_gemm128<<<gg, 256, 0, stream>>>(hb, Wl1, nullptr, yl);
  k_gemm128<<<gg, 256, 0, stream>>>(hb, Wr1, bl1, yr);
  k_agg128<<<(NN * 64) / 256, 256, 0, stream>>>(yl, yr, csroff, csrsrc, invd, hb, 1);
  // layer 2 (transform-first: aggregate in 32-dim space) + fused log_softmax
  k_gemm32<<<(NN + 63) / 64, 128, 0, stream>>>(hb, Wl2, Wr2, bl2, yl, yr);
  k_agg32_lsm<<<(NN * 32) / 256, 256, 0, stream>>>(yl, yr, csroff, csrsrc, invd,
                                                   (float*)d_out);
}

// Round 2
// 708.409 us; speedup vs baseline: 1.1997x; 1.1997x over previous
//
#include <hip/hip_runtime.h>
#include <hip/hip_bf16.h>
#include <math.h>

#define NN 100000
#define NE 1600000
#define DH 128
#define DOUT 32

// ---------- bf16 helpers (bit-exact, no lib calls) ----------
__device__ __forceinline__ unsigned short f2bf(float f) {
  union { float f; unsigned int i; } v; v.f = f;
  unsigned int i = v.i;
  unsigned int r = (i + 0x7FFFu + ((i >> 16) & 1u)) >> 16;   // RNE
  return (unsigned short)r;
}
__device__ __forceinline__ float bflo(unsigned int u) {
  union { unsigned int i; float f; } v; v.i = u << 16; return v.f;
}
__device__ __forceinline__ float bfhi(unsigned int u) {
  union { unsigned int i; float f; } v; v.i = u & 0xFFFF0000u; return v.f;
}
__device__ __forceinline__ float bf1(unsigned short u) {
  union { unsigned int i; float f; } v; v.i = ((unsigned int)u) << 16; return v.f;
}

// ---------------- CSR build ----------------

__global__ void k_count(const int* __restrict__ dst, int* __restrict__ cnt) {
  int e = blockIdx.x * 256 + threadIdx.x;
  if (e < NE) {
    int d = dst[e];
    d = d < 0 ? 0 : (d >= NN ? NN - 1 : d);   // defensive clamp
    atomicAdd(&cnt[d], 1);
  }
}

#define CHUNK 1024

__global__ void k_scan_sum(const int* __restrict__ cnt, int* __restrict__ parts) {
  __shared__ int sd[256];
  int b = blockIdx.x, t = threadIdx.x;
  int base = b * CHUNK;
  int s = 0;
  for (int i = t; i < CHUNK; i += 256) {
    int idx = base + i;
    s += (idx < NN) ? cnt[idx] : 0;
  }
  sd[t] = s;
  __syncthreads();
  for (int st = 128; st; st >>= 1) {
    if (t < st) sd[t] += sd[t + st];
    __syncthreads();
  }
  if (t == 0) parts[b] = sd[0];
}

// parallel exclusive scan over the (<=128) chunk partials
__global__ void k_scan_top(int* __restrict__ parts, int nb, int* __restrict__ csroff) {
  __shared__ int sd[128];
  int t = threadIdx.x;
  int v = (t < nb) ? parts[t] : 0;
  sd[t] = v;
  __syncthreads();
  for (int st = 1; st < 128; st <<= 1) {
    int x = (t >= st) ? sd[t - st] : 0;
    __syncthreads();
    sd[t] += x;
    __syncthreads();
  }
  if (t < nb) parts[t] = sd[t] - v;          // exclusive
  if (t == nb - 1) csroff[NN] = sd[t];       // == NE
}

__global__ void k_scan_chunks(const int* __restrict__ cnt, const int* __restrict__ parts,
                              int* __restrict__ csroff) {
  __shared__ int sums[256];
  int b = blockIdx.x, t = threadIdx.x;
  int base = b * CHUNK;
  int v[4]; int loc = 0;
  #pragma unroll
  for (int i = 0; i < 4; i++) {
    int idx = base + t * 4 + i;
    v[i] = (idx < NN) ? cnt[idx] : 0;
    loc += v[i];
  }
  sums[t] = loc;
  __syncthreads();
  for (int st = 1; st < 256; st <<= 1) {
    int x = (t >= st) ? sums[t - st] : 0;
    __syncthreads();
    sums[t] += x;
    __syncthreads();
  }
  int run = (t ? sums[t - 1] : 0) + parts[b];
  #pragma unroll
  for (int i = 0; i < 4; i++) {
    int idx = base + t * 4 + i;
    if (idx < NN) csroff[idx] = run;
    run += v[i];
  }
}

__global__ void k_invdeg(const int* __restrict__ cnt, float* __restrict__ invd) {
  int i = blockIdx.x * 256 + threadIdx.x;
  if (i < NN) {
    int d = cnt[i];
    invd[i] = 1.0f / (float)(d < 1 ? 1 : d);
  }
}

__global__ void k_fill(const int* __restrict__ src, const int* __restrict__ dst,
                       const int* __restrict__ csroff, int* __restrict__ cursor,
                       int* __restrict__ csrsrc) {
  int e = blockIdx.x * 256 + threadIdx.x;
  if (e < NE) {
    int d = dst[e];
    d = d < 0 ? 0 : (d >= NN ? NN - 1 : d);
    int s = src[e];
    s = s < 0 ? 0 : (s >= NN ? NN - 1 : s);
    int p = csroff[d] + atomicAdd(&cursor[d], 1);
    csrsrc[p] = s;
  }
}

// ---------------- GEMM: [NN,128] @ [128,128] (+bias) ----------------
// block tile: 128 nodes x 128 cols; 256 thr = 16 tx (8 cols) x 16 ty (8 nodes)
// W LDS swizzle f(c) = c + 4*(c>>5) breaks the 4-way conflict to 2-way (free).

__device__ __forceinline__ int wswz(int c) { return c + ((c >> 5) << 2); }

template <int BF16OUT>
__global__ __launch_bounds__(256) void k_gemm128_t(
    const float* __restrict__ A, const float* __restrict__ W,
    const float* __restrict__ bias, void* __restrict__ outp) {
  __shared__ float sW[16 * 140];
  __shared__ float sX[16 * 132];
  int tid = threadIdx.x;
  int nb  = blockIdx.x * 128;
  int tx = tid & 15, ty = tid >> 4;

  float acc[8][8];
  #pragma unroll
  for (int i = 0; i < 8; i++)
    #pragma unroll
    for (int j = 0; j < 8; j++) acc[i][j] = 0.0f;

  for (int kb = 0; kb < 8; kb++) {
    __syncthreads();
    #pragma unroll
    for (int i = 0; i < 2; i++) {
      int j = i * 256 + tid;            // 0..511 f4s
      int node = j >> 2;
      int k4 = (j & 3) * 4;
      float4 xv = make_float4(0.f, 0.f, 0.f, 0.f);
      int gn = nb + node;
      if (gn < NN) xv = *(const float4*)&A[gn * 128 + kb * 16 + k4];
      sX[(k4 + 0) * 132 + node] = xv.x;
      sX[(k4 + 1) * 132 + node] = xv.y;
      sX[(k4 + 2) * 132 + node] = xv.z;
      sX[(k4 + 3) * 132 + node] = xv.w;
    }
    #pragma unroll
    for (int i = 0; i < 2; i++) {
      int j = i * 256 + tid;            // 0..511 f4s
      int k = j >> 5;
      int c4 = (j & 31) * 4;
      float4 wv = *(const float4*)&W[(kb * 16 + k) * 128 + c4];
      *(float4*)&sW[k * 140 + wswz(c4)] = wv;
    }
    __syncthreads();
    #pragma unroll
    for (int kk = 0; kk < 16; kk++) {
      float4 xa = *(const float4*)&sX[kk * 132 + 8 * ty];
      float4 xb = *(const float4*)&sX[kk * 132 + 8 * ty + 4];
      int cb = 8 * tx;
      float4 wa = *(const float4*)&sW[kk * 140 + wswz(cb)];
      float4 wb = *(const float4*)&sW[kk * 140 + wswz(cb + 4)];
      float xv[8] = {xa.x, xa.y, xa.z, xa.w, xb.x, xb.y, xb.z, xb.w};
      float wv[8] = {wa.x, wa.y, wa.z, wa.w, wb.x, wb.y, wb.z, wb.w};
      #pragma unroll
      for (int i = 0; i < 8; i++)
        #pragma unroll
        for (int j = 0; j < 8; j++)
          acc[i][j] += xv[i] * wv[j];
    }
  }
  float bs[8];
  #pragma unroll
  for (int j = 0; j < 8; j++) bs[j] = bias ? bias[8 * tx + j] : 0.0f;
  #pragma unroll
  for (int i = 0; i < 8; i++) {
    int gn = nb + 8 * ty + i;
    if (gn < NN) {
      if (BF16OUT) {
        unsigned short* out = (unsigned short*)outp;
        union { unsigned short us[8]; uint4 v; } o;
        #pragma unroll
        for (int j = 0; j < 8; j++) o.us[j] = f2bf(acc[i][j] + bs[j]);
        *(uint4*)&out[gn * 128 + 8 * tx] = o.v;
      } else {
        float* out = (float*)outp;
        float4 o0 = make_float4(acc[i][0] + bs[0], acc[i][1] + bs[1],
                                acc[i][2] + bs[2], acc[i][3] + bs[3]);
        float4 o1 = make_float4(acc[i][4] + bs[4], acc[i][5] + bs[5],
                                acc[i][6] + bs[6], acc[i][7] + bs[7]);
        *(float4*)&out[gn * 128 + 8 * tx]     = o0;
        *(float4*)&out[gn * 128 + 8 * tx + 4] = o1;
      }
    }
  }
}

// ---------------- dual GEMM: [NN,128] @ [128,32] for Wl2 / Wr2 ----------------
// yl -> bf16 (gathered next), yr -> fp32

__global__ __launch_bounds__(128) void k_gemm32(
    const float* __restrict__ A, const float* __restrict__ Wl,
    const float* __restrict__ Wr, const float* __restrict__ bias,
    unsigned short* __restrict__ yl, float* __restrict__ yr) {
  __shared__ float sAT[64 * 68];
  __shared__ float sWl[64 * 36];
  __shared__ float sWr[64 * 36];
  int tid = threadIdx.x;
  int nb  = blockIdx.x * 64;
  int ng = tid >> 3;
  int cg = tid & 7;

  float accl[4][4], accr[4][4];
  #pragma unroll
  for (int i = 0; i < 4; i++)
    #pragma unroll
    for (int j = 0; j < 4; j++) { accl[i][j] = 0.f; accr[i][j] = 0.f; }

  for (int kb = 0; kb < 2; kb++) {
    __syncthreads();
    #pragma unroll
    for (int i = 0; i < 8; i++) {
      int j = i * 128 + tid;
      int node = j >> 4;
      int k4 = (j & 15) * 4;
      float4 v = make_float4(0.f, 0.f, 0.f, 0.f);
      int gn = nb + node;
      if (gn < NN) v = *(const float4*)&A[gn * 128 + kb * 64 + k4];
      sAT[(k4 + 0) * 68 + node] = v.x;
      sAT[(k4 + 1) * 68 + node] = v.y;
      sAT[(k4 + 2) * 68 + node] = v.z;
      sAT[(k4 + 3) * 68 + node] = v.w;
    }
    #pragma unroll
    for (int i = 0; i < 4; i++) {
      int j = i * 128 + tid;
      int k = j >> 3;
      int c4 = (j & 7) * 4;
      *(float4*)&sWl[k * 36 + c4] = *(const float4*)&Wl[(kb * 64 + k) * 32 + c4];
      *(float4*)&sWr[k * 36 + c4] = *(const float4*)&Wr[(kb * 64 + k) * 32 + c4];
    }
    __syncthreads();
    #pragma unroll 8
    for (int kk = 0; kk < 64; kk++) {
      float4 a  = *(const float4*)&sAT[kk * 68 + 4 * ng];
      float4 wl = *(const float4*)&sWl[kk * 36 + 4 * cg];
      float4 wr = *(const float4*)&sWr[kk * 36 + 4 * cg];
      float av[4] = {a.x, a.y, a.z, a.w};
      float wlv[4] = {wl.x, wl.y, wl.z, wl.w};
      float wrv[4] = {wr.x, wr.y, wr.z, wr.w};
      #pragma unroll
      for (int i = 0; i < 4; i++)
        #pragma unroll
        for (int j = 0; j < 4; j++) {
          accl[i][j] += av[i] * wlv[j];
          accr[i][j] += av[i] * wrv[j];
        }
    }
  }
  float bs[4];
  #pragma unroll
  for (int j = 0; j < 4; j++) bs[j] = bias[4 * cg + j];
  #pragma unroll
  for (int i = 0; i < 4; i++) {
    int gn = nb + 4 * ng + i;
    if (gn < NN) {
      union { unsigned short us[4]; uint2 v; } o;
      #pragma unroll
      for (int j = 0; j < 4; j++) o.us[j] = f2bf(accl[i][j]);
      *(uint2*)&yl[gn * 32 + 4 * cg] = o.v;
      *(float4*)&yr[gn * 32 + 4 * cg] =
          make_float4(accr[i][0] + bs[0], accr[i][1] + bs[1],
                      accr[i][2] + bs[2], accr[i][3] + bs[3]);
    }
  }
}

// ---------------- pull aggregation, 128-dim (bf16 gather) ----------------
// one wave per node; lane holds cols {2*lane, 2*lane+1} as one packed uint.
// 4-deep edge unroll for 4 outstanding gathers per wave.

__global__ __launch_bounds__(256) void k_agg128(
    const unsigned short* __restrict__ yl, const float* __restrict__ yr,
    const int* __restrict__ off, const int* __restrict__ csr,
    const float* __restrict__ invd, float* __restrict__ out, int relu) {
  int wid  = (blockIdx.x * 256 + threadIdx.x) >> 6;
  int lane = threadIdx.x & 63;
  if (wid >= NN) return;
  int beg = off[wid], end = off[wid + 1];
  const unsigned int* ylp = (const unsigned int*)yl;   // row stride 64 uints
  float ax0 = 0.f, ay0 = 0.f, ax1 = 0.f, ay1 = 0.f;
  float ax2 = 0.f, ay2 = 0.f, ax3 = 0.f, ay3 = 0.f;
  int e = beg;
  for (; e + 3 < end; e += 4) {
    int s0 = csr[e], s1 = csr[e + 1], s2 = csr[e + 2], s3 = csr[e + 3];
    unsigned int u0 = ylp[s0 * 64 + lane];
    unsigned int u1 = ylp[s1 * 64 + lane];
    unsigned int u2 = ylp[s2 * 64 + lane];
    unsigned int u3 = ylp[s3 * 64 + lane];
    ax0 += bflo(u0); ay0 += bfhi(u0);
    ax1 += bflo(u1); ay1 += bfhi(u1);
    ax2 += bflo(u2); ay2 += bfhi(u2);
    ax3 += bflo(u3); ay3 += bfhi(u3);
  }
  for (; e < end; e++) {
    int s = csr[e];
    unsigned int u = ylp[s * 64 + lane];
    ax0 += bflo(u); ay0 += bfhi(u);
  }
  float sc = invd[wid];
  float2 r = ((const float2*)yr)[wid * 64 + lane];
  float vx = ((ax0 + ax1) + (ax2 + ax3)) * sc + r.x;
  float vy = ((ay0 + ay1) + (ay2 + ay3)) * sc + r.y;
  if (relu) { vx = fmaxf(vx, 0.f); vy = fmaxf(vy, 0.f); }
  ((float2*)out)[wid * 64 + lane] = make_float2(vx, vy);
}

// ---------------- 32-dim aggregation + bias + log_softmax (fused) ----------------

__global__ __launch_bounds__(256) void k_agg32_lsm(
    const unsigned short* __restrict__ yl, const float* __restrict__ yr,
    const int* __restrict__ off, const int* __restrict__ csr,
    const float* __restrict__ invd, float* __restrict__ out) {
  int row  = (blockIdx.x * 256 + threadIdx.x) >> 5;
  int lane = threadIdx.x & 31;
  if (row >= NN) return;
  int beg = off[row], end = off[row + 1];
  float a0 = 0.f, a1 = 0.f, a2 = 0.f, a3 = 0.f;
  int e = beg;
  for (; e + 3 < end; e += 4) {
    int s0 = csr[e], s1 = csr[e + 1], s2 = csr[e + 2], s3 = csr[e + 3];
    a0 += bf1(yl[s0 * 32 + lane]);
    a1 += bf1(yl[s1 * 32 + lane]);
    a2 += bf1(yl[s2 * 32 + lane]);
    a3 += bf1(yl[s3 * 32 + lane]);
  }
  for (; e < end; e++) a0 += bf1(yl[csr[e] * 32 + lane]);
  float v = ((a0 + a1) + (a2 + a3)) * invd[row] + yr[row * 32 + lane];
  float m = v;
  #pragma unroll
  for (int o = 16; o; o >>= 1) m = fmaxf(m, __shfl_xor(m, o, 32));
  float ex = expf(v - m);
  float s = ex;
  #pragma unroll
  for (int o = 16; o; o >>= 1) s += __shfl_xor(s, o, 32);
  out[row * 32 + lane] = v - m - logf(s);
}

// ---------------- launch ----------------

extern "C" void kernel_launch(void* const* d_in, const int* in_sizes, int n_in,
                              void* d_out, int out_size, void* d_ws, size_t ws_size,
                              hipStream_t stream) {
  (void)in_sizes; (void)n_in; (void)out_size; (void)ws_size;
  const float* x   = (const float*)d_in[0];
  const int*   ei  = (const int*)d_in[1];
  const float* Wl0 = (const float*)d_in[2];
  const float* bl0 = (const float*)d_in[3];
  const float* Wr0 = (const float*)d_in[4];
  const float* Wl1 = (const float*)d_in[5];
  const float* bl1 = (const float*)d_in[6];
  const float* Wr1 = (const float*)d_in[7];
  const float* Wl2 = (const float*)d_in[8];
  const float* bl2 = (const float*)d_in[9];
  const float* Wr2 = (const float*)d_in[10];
  const int* srcI = ei;
  const int* dstI = ei + NE;

  char* w = (char*)d_ws;
  int*   cnt    = (int*)(w + 0);
  int*   cursor = (int*)(w + (512 << 10));
  int*   csroff = (int*)(w + (1024 << 10));
  float* invd   = (float*)(w + (1536 << 10));
  int*   parts  = (int*)(w + (2048 << 10));
  int*   csrsrc = (int*)(w + (2560 << 10));
  unsigned short* ylb = (unsigned short*)(w + (size_t)(10)  * 1024 * 1024); // bf16, 25.6 MB
  float* yr     = (float*)(w + (size_t)(64)  * 1024 * 1024);               // fp32, 51.2 MB
  float* hb     = (float*)(w + (size_t)(118) * 1024 * 1024);               // fp32, 51.2 MB

  hipMemsetAsync(cnt, 0, NN * sizeof(int), stream);
  hipMemsetAsync(cursor, 0, NN * sizeof(int), stream);

  int nch = (NN + CHUNK - 1) / CHUNK;   // 98
  k_count<<<(NE + 255) / 256, 256, 0, stream>>>(dstI, cnt);
  k_scan_sum<<<nch, 256, 0, stream>>>(cnt, parts);
  k_scan_top<<<1, 128, 0, stream>>>(parts, nch, csroff);
  k_scan_chunks<<<nch, 256, 0, stream>>>(cnt, parts, csroff);
  k_invdeg<<<(NN + 255) / 256, 256, 0, stream>>>(cnt, invd);
  k_fill<<<(NE + 255) / 256, 256, 0, stream>>>(srcI, dstI, csroff, cursor, csrsrc);

  dim3 gg((NN + 127) / 128);
  // layer 0
  k_gemm128_t<1><<<gg, 256, 0, stream>>>(x, Wl0, nullptr, ylb);
  k_gemm128_t<0><<<gg, 256, 0, stream>>>(x, Wr0, bl0, yr);
  k_agg128<<<(NN * 64) / 256, 256, 0, stream>>>(ylb, yr, csroff, csrsrc, invd, hb, 1);
  // layer 1
  k_gemm128_t<1><<<gg, 256, 0, stream>>>(hb, Wl1, nullptr, ylb);
  k_gemm128_t<0><<<gg, 256, 0, stream>>>(hb, Wr1, bl1, yr);
  k_agg128<<<(NN * 64) / 256, 256, 0, stream>>>(ylb, yr, csroff, csrsrc, invd, hb, 1);
  // layer 2 (transform-first, 32-dim aggregation) + fused log_softmax
  k_gemm32<<<(NN + 63) / 64, 128, 0, stream>>>(hb, Wl2, Wr2, bl2, ylb, yr);
  k_agg32_lsm<<<(NN * 32) / 256, 256, 0, stream>>>(ylb, yr, csroff, csrsrc, invd,
                                                   (float*)d_out);
}